// Round 12
// baseline (275.661 us; speedup 1.0000x reference)
//
#include <hip/hip_runtime.h>
#include <stdint.h>

typedef __bf16 bf16;
typedef __bf16 bf16x4 __attribute__((ext_vector_type(4)));
typedef __bf16 bf16x8 __attribute__((ext_vector_type(8)));
typedef float f32x4 __attribute__((ext_vector_type(4)));

#define CN 524288    // C*N = 512*1024 (per-batch x elements)
#define NPIX 1024
#define CCH 512

// ---- async global->LDS, 16B per lane ----
__device__ __forceinline__ void gload_lds16(const void* g, void* l) {
  auto gp = reinterpret_cast<const __attribute__((address_space(1))) uint32_t*>(
      reinterpret_cast<uintptr_t>(g));
  auto lp = reinterpret_cast<__attribute__((address_space(3))) uint32_t*>(
      static_cast<uint32_t>(reinterpret_cast<uintptr_t>(l)));
  __builtin_amdgcn_global_load_lds(gp, lp, 16, 0, 0);
}

// ======================================================================
// gemm_bt (r9/r11 engine): C[i,j] = sum_k A[i,k] * Bt[j,k]
// 256x256 tile, BK=64, 8 waves, dbuf LDS 128KB, counted vmcnt(4),
// 16x16x32 bf16 MFMA, verified seg-XOR swizzle (0 conflicts on HW).
// EPI 0: kg+v  (j<512 -> kgT[i][j];  j>=512 -> v[j-512][i] + bias)
// EPI 1: U = exp((S + c[j])*scale) bf16 + partial row-sums -> pst
//        (c[j] = sum of 32 group-partials in resid/cpart)
// EPI 2: PV    (bf16 out = acc / rowsum; rowsum = sum of 4 pst)
// EPI 3: proj  (fp32 out + proj_b[i] + resid)
// ======================================================================
template<int EPI>
__global__ __launch_bounds__(512, 2)
void gemm_bt(const bf16* __restrict__ A, int lda, long long sA,
             const bf16* __restrict__ Bt, int ldb, long long sB,
             char* __restrict__ Cp, long long sC,
             char* __restrict__ C2p, long long sC2,
             const float* __restrict__ bias,
             const float* __restrict__ resid,
             float* __restrict__ pst,
             int K, float scale)
{
  __shared__ __align__(16) bf16 As[2 * 16384];   // 2 x [256][64]
  __shared__ __align__(16) bf16 Bs[2 * 16384];
  const int t = threadIdx.x;
  const int w = t >> 6;
  const int l = t & 63;
  const int z = blockIdx.z;
  A  += (long long)z * sA;
  Bt += (long long)z * sB;
  Cp += (long long)z * sC;
  if (C2p) C2p += (long long)z * sC2;
  const float* residb = (EPI == 3) ? (resid + (long long)z * CN) : nullptr;
  const float* cpartb = (EPI == 1) ? (resid + (long long)z * 32768) : nullptr;

  const int row0 = blockIdx.x * 256;
  const int col0 = blockIdx.y * 256;
  const int wr = w >> 2;              // 0..1 : wave row group (128 rows)
  const int wc = w & 3;               // 0..3 : wave col group (64 cols)

  f32x4 acc[8][4] = {};

  // ---- staging geometry: chunk = 64 rows x 64 cols bf16 = 8KB ----
  const int wv  = w;                  // wave id 0..7
  const int srow = (l >> 3);          // 0..7 row within wave's 8-row slice
  const int segp = ((l & 7) ^ srow) << 3;   // pre-swizzled k-seg (elements)
  const bf16* baseA = A  + (long long)(row0 + wv * 8 + srow) * lda + segp;
  const bf16* baseB = Bt + (long long)(col0 + wv * 8 + srow) * ldb + segp;

  auto stageA = [&](int kt1, int buf, int c) {
    gload_lds16(baseA + (long long)c * 64 * lda + kt1 * 64,
                &As[buf * 16384 + c * 4096 + wv * 512]);
  };
  auto stageB = [&](int kt1, int buf, int c) {
    gload_lds16(baseB + (long long)c * 64 * ldb + kt1 * 64,
                &Bs[buf * 16384 + c * 4096 + wv * 512]);
  };

  // ---- fragment-read geometry ----
  const int lrow = l & 15;
  const int lx = l & 7;
  const int s0 = (((l >> 4)) ^ lx) << 3;       // kk=0 swizzled seg offset
  const int s1 = (((l >> 4) + 4) ^ lx) << 3;   // kk=1

  const int nt = K >> 6;

  // prologue: tile 0 -> buf 0
  #pragma unroll
  for (int c = 0; c < 4; ++c) stageB(0, 0, c);
  #pragma unroll
  for (int c = 0; c < 4; ++c) stageA(0, 0, c);

  #pragma unroll 1
  for (int kt = 0; kt < nt; ++kt) {
    const int cur = kt & 1, nxt = cur ^ 1;
    const bool pf = (kt + 1) < nt;
    if (pf) {
      #pragma unroll
      for (int c = 0; c < 4; ++c) stageB(kt + 1, nxt, c);
      asm volatile("s_waitcnt vmcnt(4)" ::: "memory");
    } else {
      asm volatile("s_waitcnt vmcnt(0)" ::: "memory");
    }
    __builtin_amdgcn_sched_barrier(0);
    __builtin_amdgcn_s_barrier();
    asm volatile("" ::: "memory");

    const int ca = cur * 16384;
    bf16x8 bF0[4], bF1[4], aF0[4], aF1[4];
    #pragma unroll
    for (int nf = 0; nf < 4; ++nf) {
      const int r = wc * 64 + nf * 16 + lrow;
      bF0[nf] = *(const bf16x8*)&Bs[ca + r * 64 + s0];
      bF1[nf] = *(const bf16x8*)&Bs[ca + r * 64 + s1];
    }
    #pragma unroll
    for (int mf = 0; mf < 4; ++mf) {
      const int r = wr * 128 + mf * 16 + lrow;
      aF0[mf] = *(const bf16x8*)&As[ca + r * 64 + s0];
      aF1[mf] = *(const bf16x8*)&As[ca + r * 64 + s1];
    }
    __builtin_amdgcn_s_setprio(1);
    #pragma unroll
    for (int mf = 0; mf < 4; ++mf)
      #pragma unroll
      for (int nf = 0; nf < 4; ++nf)
        acc[mf][nf] = __builtin_amdgcn_mfma_f32_16x16x32_bf16(
            aF1[mf], bF1[nf],
            __builtin_amdgcn_mfma_f32_16x16x32_bf16(aF0[mf], bF0[nf], acc[mf][nf], 0, 0, 0),
            0, 0, 0);
    __builtin_amdgcn_s_setprio(0);
    if (pf) {
      #pragma unroll
      for (int c = 0; c < 4; ++c) stageA(kt + 1, nxt, c);
    }
    #pragma unroll
    for (int mf = 0; mf < 4; ++mf) {
      const int r = wr * 128 + 64 + mf * 16 + lrow;
      aF0[mf] = *(const bf16x8*)&As[ca + r * 64 + s0];
      aF1[mf] = *(const bf16x8*)&As[ca + r * 64 + s1];
    }
    __builtin_amdgcn_s_setprio(1);
    #pragma unroll
    for (int mf = 0; mf < 4; ++mf)
      #pragma unroll
      for (int nf = 0; nf < 4; ++nf)
        acc[4 + mf][nf] = __builtin_amdgcn_mfma_f32_16x16x32_bf16(
            aF1[mf], bF1[nf],
            __builtin_amdgcn_mfma_f32_16x16x32_bf16(aF0[mf], bF0[nf], acc[4 + mf][nf], 0, 0, 0),
            0, 0, 0);
    __builtin_amdgcn_s_setprio(0);
    asm volatile("" ::: "memory");
    __builtin_amdgcn_sched_barrier(0);
    __builtin_amdgcn_s_barrier();
  }

  const int ci = (l >> 4) * 4;
  const int cj = l & 15;

  if constexpr (EPI == 1) {
    // ---- c[j] combine (32 group partials), then U = exp((acc+c)*scale)
    //      + deterministic partial row-sums ----
    float cs[4];
    #pragma unroll
    for (int nf = 0; nf < 4; ++nf) {
      const int j = col0 + wc * 64 + nf * 16 + cj;
      float s = 0.f;
      #pragma unroll
      for (int g = 0; g < 32; ++g) s += cpartb[g * 1024 + j];
      cs[nf] = s;
    }
    bf16* sp = (bf16*)Cp;
    float* part = (float*)As;          // reuse LDS: part[wc*256 + localrow]
    #pragma unroll
    for (int mf = 0; mf < 8; ++mf) {
      const int lr0 = wr * 128 + mf * 16 + ci;   // tile-local row
      #pragma unroll
      for (int r = 0; r < 4; ++r) {
        float s = 0.f;
        #pragma unroll
        for (int nf = 0; nf < 4; ++nf) {
          const int j = col0 + wc * 64 + nf * 16 + cj;
          const float u = __expf((acc[mf][nf][r] + cs[nf]) * scale);
          const bf16 ub = (bf16)u;
          sp[(row0 + lr0 + r) * NPIX + j] = ub;
          s += (float)ub;
        }
        s += __shfl_xor(s, 1); s += __shfl_xor(s, 2);
        s += __shfl_xor(s, 4); s += __shfl_xor(s, 8);
        if (cj == 0) part[wc * 256 + lr0 + r] = s;
      }
    }
    __syncthreads();
    if (t < 256)
      pst[((long long)z * 4 + blockIdx.y) * 1024 + row0 + t]
          = part[t] + part[256 + t] + part[512 + t] + part[768 + t];
    return;
  }

  #pragma unroll
  for (int mf = 0; mf < 8; ++mf) {
    const int i0 = row0 + wr * 128 + mf * 16 + ci;
    if constexpr (EPI == 2) {
      const float* pz = pst + (long long)z * 4096;
      #pragma unroll
      for (int r = 0; r < 4; ++r) {
        const int row = i0 + r;
        const float is = 1.f / (pz[row] + pz[1024 + row] +
                                pz[2048 + row] + pz[3072 + row]);
        bf16* hp = (bf16*)Cp;
        #pragma unroll
        for (int nf = 0; nf < 4; ++nf) {
          const int j = col0 + wc * 64 + nf * 16 + cj;
          hp[row * CCH + j] = (bf16)(acc[mf][nf][r] * is);
        }
      }
    } else {
      #pragma unroll
      for (int nf = 0; nf < 4; ++nf) {
        const int j = col0 + wc * 64 + nf * 16 + cj;
        const f32x4 a = acc[mf][nf];
        if constexpr (EPI == 0) {
          if (j < 512) {
            bf16* q = (bf16*)Cp;
            #pragma unroll
            for (int r = 0; r < 4; ++r)
              q[(i0 + r) * CCH + j] = (bf16)a[r];
          } else {
            const float bj = bias[512 + j];   // = qkv_b[1024 + (j-512)]
            bf16* vb = (bf16*)C2p;
            #pragma unroll
            for (int r = 0; r < 4; ++r)
              vb[(j - 512) * NPIX + (i0 + r)] = (bf16)(a[r] + bj);
          }
        } else {
          float* op = (float*)Cp;
          #pragma unroll
          for (int r = 0; r < 4; ++r)
            op[(i0 + r) * NPIX + j] = a[r] + bias[i0 + r] + residb[(i0 + r) * NPIX + j];
        }
      }
    }
  }
}

// ---- fused GroupNorm + c-partials (r11-verified) ----
__global__ __launch_bounds__(256)
void gn_fused(const float* __restrict__ x, const float* __restrict__ gw,
              const float* __restrict__ gb, const float* __restrict__ u,
              bf16* __restrict__ hnT, float* __restrict__ cpart)
{
  __shared__ float xs[16 * 1024];   // 64 KB
  __shared__ float red[8];
  const int b = blockIdx.x >> 5;
  const int g = blockIdx.x & 31;
  const float* xp = x + ((long long)b * CCH + g * 16) * NPIX;
  const int t = threadIdx.x;

  float4* xsv = (float4*)xs;
  const float4* gv = (const float4*)xp;
  float s = 0.f, ss = 0.f;
  #pragma unroll
  for (int i = 0; i < 16; ++i) {
    float4 v = gv[t + i * 256];
    xsv[t + i * 256] = v;
    s  += v.x + v.y + v.z + v.w;
    ss += v.x * v.x + v.y * v.y + v.z * v.z + v.w * v.w;
  }
  #pragma unroll
  for (int o = 32; o; o >>= 1) { s += __shfl_xor(s, o); ss += __shfl_xor(ss, o); }
  if ((t & 63) == 0) { red[t >> 6] = s; red[4 + (t >> 6)] = ss; }
  __syncthreads();
  s  = red[0] + red[1] + red[2] + red[3];
  ss = red[4] + red[5] + red[6] + red[7];
  const float mean = s * (1.f / 16384.f);
  const float var  = ss * (1.f / 16384.f) - mean * mean;
  const float rstd = rsqrtf(var + 1e-5f);

  float ac[16], bc[16], uu[16];
  #pragma unroll
  for (int c = 0; c < 16; ++c) {
    const float wv = gw[g * 16 + c] * rstd;
    ac[c] = wv;
    bc[c] = gb[g * 16 + c] - mean * wv;
    uu[c] = u[g * 16 + c];
  }

  bf16* hp = hnT + (long long)b * CN + g * 16;
  float* cp = cpart + ((long long)b * 32 + g) * 1024;
  #pragma unroll
  for (int r = 0; r < 4; ++r) {
    const int n = t + r * 256;
    bf16x8 o0, o1;
    float cacc = 0.f;
    #pragma unroll
    for (int c = 0; c < 8; ++c) {
      const float v0 = xs[c * 1024 + n] * ac[c] + bc[c];
      o0[c] = (bf16)v0;
      cacc += v0 * uu[c];
    }
    #pragma unroll
    for (int c = 0; c < 8; ++c) {
      const float v1 = xs[(8 + c) * 1024 + n] * ac[8 + c] + bc[8 + c];
      o1[c] = (bf16)v1;
      cacc += v1 * uu[8 + c];
    }
    *(bf16x8*)&hp[(long long)n * CCH]     = o0;
    *(bf16x8*)&hp[(long long)n * CCH + 8] = o1;
    cp[n] = cacc;
  }
}

// ---- one-shot parallel prep: G = Wq^T Wk (fp32 acc -> bf16) + u = Wk^T bq
// grid (16,16): block owns 32x32 patch of G; 256 threads, each 1x4 outputs.
// Wq[o][c] reads: 8 distinct dwords/wave (32B span); Wk float4 reads
// coalesced 128B. All L2-hot (qkv_w rows 0..1023 = 2MB). ~6us.
// Blocks with blockIdx.x==0 additionally reduce u[d0..d0+31].
__global__ __launch_bounds__(256)
void prep_gw(const float* __restrict__ qkv_w, const float* __restrict__ qkv_b,
             bf16* __restrict__ G, float* __restrict__ u)
{
  const int c0 = blockIdx.x * 32;
  const int d0 = blockIdx.y * 32;
  const int t = threadIdx.x;
  const float* Wq = qkv_w;
  const float* Wk = qkv_w + 512 * 512;
  const int cc = c0 + (t >> 3);
  const int d4 = d0 + (t & 7) * 4;

  float a0 = 0.f, a1 = 0.f, a2 = 0.f, a3 = 0.f;
  #pragma unroll 8
  for (int o = 0; o < 512; ++o) {
    const float q = Wq[o * 512 + cc];
    const float4 k4 = *(const float4*)&Wk[o * 512 + d4];
    a0 += q * k4.x; a1 += q * k4.y; a2 += q * k4.z; a3 += q * k4.w;
  }
  bf16x4 gvw;
  gvw[0] = (bf16)a0; gvw[1] = (bf16)a1; gvw[2] = (bf16)a2; gvw[3] = (bf16)a3;
  *(bf16x4*)&G[(long long)cc * 512 + d4] = gvw;

  if (blockIdx.x == 0) {
    __shared__ float red[8][32];
    const int og = t >> 5, dd = t & 31;
    float s = 0.f;
    #pragma unroll 8
    for (int o = og * 64; o < og * 64 + 64; ++o)
      s += qkv_b[o] * Wk[o * 512 + d0 + dd];
    red[og][dd] = s;
    __syncthreads();
    if (t < 32) {
      float us = 0.f;
      #pragma unroll
      for (int i = 0; i < 8; ++i) us += red[i][t];
      u[d0 + t] = us;
    }
  }
}

// ---- fp32 -> bf16 weight conversion: W2 v-rows + proj ----
__global__ __launch_bounds__(256)
void cvt_weights(const float* __restrict__ qw, const float* __restrict__ pw,
                 bf16* __restrict__ w2v, bf16* __restrict__ pwb)
{
  const int i = blockIdx.x * 256 + threadIdx.x;
  if (i < CCH * CCH) {
    w2v[i] = (bf16)qw[1024 * 512 + i];   // Wv rows -> W2[512..1023]
    pwb[i] = (bf16)pw[i];
  }
}

extern "C" void kernel_launch(void* const* d_in, const int* in_sizes, int n_in,
                              void* d_out, int out_size, void* d_ws, size_t ws_size,
                              hipStream_t stream)
{
  const float* x      = (const float*)d_in[0];
  const float* gn_w   = (const float*)d_in[1];
  const float* gn_b   = (const float*)d_in[2];
  const float* qkv_w  = (const float*)d_in[3];
  const float* qkv_b  = (const float*)d_in[4];
  const float* proj_w = (const float*)d_in[5];
  const float* proj_b = (const float*)d_in[6];
  float* out = (float*)d_out;
  (void)in_sizes; (void)n_in; (void)out_size;

  char* ws = (char*)d_ws;
  size_t off = 0;
  auto alloc = [&](size_t bytes) -> char* {
    char* p = ws + off;
    off += (bytes + 255) & ~(size_t)255;
    return p;
  };
  bf16*  W2      = (bf16*)alloc(1024 * 512 * 2);   // [G(512) ; Wv(512)]
  bf16*  proj_wb = (bf16*)alloc(512 * 512 * 2);
  float* uvec    = (float*)alloc(512 * 4);
  const size_t fixed = off;
  // per-batch: hnT 1MB + kgT 1MB + v 1MB + U 2MB + hvT 1MB + pst 16KB + cpart 128KB
  const size_t per = 1048576ull + 1048576ull + 1048576ull + 2097152ull
                   + 1048576ull + 16384ull + 131072ull;
  int Bc = 32;
  if (ws_size > fixed) {
    size_t fit = (ws_size - fixed) / per;
    if (fit < 32) Bc = (int)fit;
  } else {
    Bc = 0;
  }
  if (Bc < 1) Bc = 1;

  bf16*  hnT    = (bf16*) alloc((size_t)Bc * 1048576);
  bf16*  kgT    = (bf16*) alloc((size_t)Bc * 1048576);
  bf16*  vbuf   = (bf16*) alloc((size_t)Bc * 1048576);
  bf16*  ubuf   = (bf16*) alloc((size_t)Bc * 2097152);
  bf16*  hvT    = (bf16*) alloc((size_t)Bc * 1048576);
  float* pstats = (float*)alloc((size_t)Bc * 16384);
  float* cpart  = (float*)alloc((size_t)Bc * 131072);

  // ---- one-time prep (parallel): G+u in one kernel, bf16 conversions ----
  prep_gw<<<dim3(16, 16), 256, 0, stream>>>(qkv_w, qkv_b, W2, uvec);
  cvt_weights<<<dim3(1024), 256, 0, stream>>>(qkv_w, proj_w, W2 + 512 * 512, proj_wb);

  const float scale = 0.044194173824159216f;  // 512^-0.5
  for (int b0 = 0; b0 < 32; b0 += Bc) {
    const int bc = (32 - b0 < Bc) ? (32 - b0) : Bc;
    const float* xb = x + (size_t)b0 * CN;

    gn_fused<<<dim3(bc * 32), 256, 0, stream>>>(xb, gn_w, gn_b, uvec, hnT, cpart);

    // kg[n][c] = hnT[n].G[c]  ;  v[c][m] = Wv[c].hnT[m] + bv  (one gemm)
    gemm_bt<0><<<dim3(4, 4, bc), 512, 0, stream>>>(
        hnT, 512, 524288, W2, 512, 0,
        (char*)kgT, 1048576, (char*)vbuf, 1048576, qkv_b, nullptr, nullptr,
        512, 1.f);

    // U[n][m] = exp((hnT[n].kgT[m] + c[m]) * scale) + partial row sums
    gemm_bt<1><<<dim3(4, 4, bc), 512, 0, stream>>>(
        hnT, 512, 524288, kgT, 512, 524288,
        (char*)ubuf, 2097152, nullptr, 0, nullptr, cpart, pstats,
        512, scale);

    // hvT[n][c] = (U[n][:] . v[c][:]) / rowsum[n]
    gemm_bt<2><<<dim3(4, 2, bc), 512, 0, stream>>>(
        ubuf, 1024, 1048576, vbuf, 1024, 524288,
        (char*)hvT, 1048576, nullptr, 0, nullptr, nullptr, pstats,
        1024, 1.f);

    // out[c][n] = proj_w[c][:] . hvT[n][:] + proj_b[c] + x[c][n]
    gemm_bt<3><<<dim3(2, 4, bc), 512, 0, stream>>>(
        proj_wb, 512, 0, hvT, 512, 524288,
        (char*)(out + (size_t)b0 * CN), 2097152, nullptr, 0, proj_b, xb,
        nullptr, 512, 1.f);
  }
}

// Round 14
// 231.466 us; speedup vs baseline: 1.1909x; 1.1909x over previous
//
#include <hip/hip_runtime.h>
#include <stdint.h>

typedef __bf16 bf16;
typedef __bf16 bf16x4 __attribute__((ext_vector_type(4)));
typedef __bf16 bf16x8 __attribute__((ext_vector_type(8)));
typedef float f32x4 __attribute__((ext_vector_type(4)));

#define CN 524288    // C*N = 512*1024 (per-batch x elements)
#define NPIX 1024
#define CCH 512

// ---- async global->LDS, 16B per lane ----
__device__ __forceinline__ void gload_lds16(const void* g, void* l) {
  auto gp = reinterpret_cast<const __attribute__((address_space(1))) uint32_t*>(
      reinterpret_cast<uintptr_t>(g));
  auto lp = reinterpret_cast<__attribute__((address_space(3))) uint32_t*>(
      static_cast<uint32_t>(reinterpret_cast<uintptr_t>(l)));
  __builtin_amdgcn_global_load_lds(gp, lp, 16, 0, 0);
}

// ======================================================================
// gemm_bt (r9 engine + XCD-chunk swizzle): C[i,j] = sum_k A[i,k]*Bt[j,k]
// 256x256 tile, BK=64, 8 waves, dbuf LDS 128KB, counted vmcnt(4),
// 16x16x32 bf16 MFMA, verified seg-XOR swizzle (0 conflicts on HW).
// Block-id swizzle: lin = (lin&7)*(nwg/8) + lin>>3  (nwg%8==0 for all
// launch configs here) -> each XCD processes a contiguous work chunk.
// NOTE stride units: sA/sB are ELEMENTS (bf16), sC/sC2 are BYTES.
// EPI 0: QKV   (bias; j<1024 -> qkT[i][j], else v[j-1024][i])
// EPI 1: U = exp(S*scale) bf16 (ld=1024) + per-block partial row-sums
//        -> pst[(z*4+by)*1024 + row]  (deterministic, no atomics)
// EPI 2: PV    (bf16 out = acc / rowsum, ld=512; rowsum = sum of 4 pst)
// EPI 3: proj  (fp32 out + proj_b[i] + resid)
// ======================================================================
template<int EPI>
__global__ __launch_bounds__(512, 2)
void gemm_bt(const bf16* __restrict__ A, int lda, long long sA,
             const bf16* __restrict__ Bt, int ldb, long long sB,
             char* __restrict__ Cp, long long sC,
             char* __restrict__ C2p, long long sC2,
             const float* __restrict__ bias,
             const float* __restrict__ resid,
             float* __restrict__ pst,
             int K, float scale)
{
  __shared__ __align__(16) bf16 As[2 * 16384];   // 2 x [256][64]
  __shared__ __align__(16) bf16 Bs[2 * 16384];
  const int t = threadIdx.x;
  const int w = t >> 6;
  const int l = t & 63;

  // ---- XCD-chunk bijective swizzle (nwg % 8 == 0 guaranteed) ----
  const int gx = gridDim.x, gy = gridDim.y;
  const int nwg = gx * gy * gridDim.z;
  int lin = blockIdx.x + gx * (blockIdx.y + gy * blockIdx.z);
  lin = (lin & 7) * (nwg >> 3) + (lin >> 3);
  const int bx = lin % gx;
  const int by = (lin / gx) % gy;
  const int z  = lin / (gx * gy);

  A  += (long long)z * sA;
  Bt += (long long)z * sB;
  Cp += (long long)z * sC;
  if (C2p) C2p += (long long)z * sC2;
  const float* residb = (EPI == 3) ? (resid + (long long)z * CN) : nullptr;

  const int row0 = bx * 256;
  const int col0 = by * 256;
  const int wr = w >> 2;              // 0..1 : wave row group (128 rows)
  const int wc = w & 3;               // 0..3 : wave col group (64 cols)

  f32x4 acc[8][4] = {};

  // ---- staging geometry: chunk = 64 rows x 64 cols bf16 = 8KB ----
  const int wv  = w;                  // wave id 0..7
  const int srow = (l >> 3);          // 0..7 row within wave's 8-row slice
  const int segp = ((l & 7) ^ srow) << 3;   // pre-swizzled k-seg (elements)
  const bf16* baseA = A  + (long long)(row0 + wv * 8 + srow) * lda + segp;
  const bf16* baseB = Bt + (long long)(col0 + wv * 8 + srow) * ldb + segp;

  auto stageA = [&](int kt1, int buf, int c) {
    gload_lds16(baseA + (long long)c * 64 * lda + kt1 * 64,
                &As[buf * 16384 + c * 4096 + wv * 512]);
  };
  auto stageB = [&](int kt1, int buf, int c) {
    gload_lds16(baseB + (long long)c * 64 * ldb + kt1 * 64,
                &Bs[buf * 16384 + c * 4096 + wv * 512]);
  };

  // ---- fragment-read geometry ----
  const int lrow = l & 15;
  const int lx = l & 7;
  const int s0 = (((l >> 4)) ^ lx) << 3;       // kk=0 swizzled seg offset
  const int s1 = (((l >> 4) + 4) ^ lx) << 3;   // kk=1

  const int nt = K >> 6;

  // prologue: tile 0 -> buf 0
  #pragma unroll
  for (int c = 0; c < 4; ++c) stageB(0, 0, c);
  #pragma unroll
  for (int c = 0; c < 4; ++c) stageA(0, 0, c);

  #pragma unroll 1
  for (int kt = 0; kt < nt; ++kt) {
    const int cur = kt & 1, nxt = cur ^ 1;
    const bool pf = (kt + 1) < nt;
    if (pf) {
      #pragma unroll
      for (int c = 0; c < 4; ++c) stageB(kt + 1, nxt, c);
      asm volatile("s_waitcnt vmcnt(4)" ::: "memory");
    } else {
      asm volatile("s_waitcnt vmcnt(0)" ::: "memory");
    }
    __builtin_amdgcn_sched_barrier(0);
    __builtin_amdgcn_s_barrier();
    asm volatile("" ::: "memory");

    const int ca = cur * 16384;
    bf16x8 bF0[4], bF1[4], aF0[4], aF1[4];
    #pragma unroll
    for (int nf = 0; nf < 4; ++nf) {
      const int r = wc * 64 + nf * 16 + lrow;
      bF0[nf] = *(const bf16x8*)&Bs[ca + r * 64 + s0];
      bF1[nf] = *(const bf16x8*)&Bs[ca + r * 64 + s1];
    }
    #pragma unroll
    for (int mf = 0; mf < 4; ++mf) {
      const int r = wr * 128 + mf * 16 + lrow;
      aF0[mf] = *(const bf16x8*)&As[ca + r * 64 + s0];
      aF1[mf] = *(const bf16x8*)&As[ca + r * 64 + s1];
    }
    __builtin_amdgcn_s_setprio(1);
    #pragma unroll
    for (int mf = 0; mf < 4; ++mf)
      #pragma unroll
      for (int nf = 0; nf < 4; ++nf)
        acc[mf][nf] = __builtin_amdgcn_mfma_f32_16x16x32_bf16(
            aF1[mf], bF1[nf],
            __builtin_amdgcn_mfma_f32_16x16x32_bf16(aF0[mf], bF0[nf], acc[mf][nf], 0, 0, 0),
            0, 0, 0);
    __builtin_amdgcn_s_setprio(0);
    if (pf) {
      #pragma unroll
      for (int c = 0; c < 4; ++c) stageA(kt + 1, nxt, c);
    }
    #pragma unroll
    for (int mf = 0; mf < 4; ++mf) {
      const int r = wr * 128 + 64 + mf * 16 + lrow;
      aF0[mf] = *(const bf16x8*)&As[ca + r * 64 + s0];
      aF1[mf] = *(const bf16x8*)&As[ca + r * 64 + s1];
    }
    __builtin_amdgcn_s_setprio(1);
    #pragma unroll
    for (int mf = 0; mf < 4; ++mf)
      #pragma unroll
      for (int nf = 0; nf < 4; ++nf)
        acc[4 + mf][nf] = __builtin_amdgcn_mfma_f32_16x16x32_bf16(
            aF1[mf], bF1[nf],
            __builtin_amdgcn_mfma_f32_16x16x32_bf16(aF0[mf], bF0[nf], acc[4 + mf][nf], 0, 0, 0),
            0, 0, 0);
    __builtin_amdgcn_s_setprio(0);
    asm volatile("" ::: "memory");
    __builtin_amdgcn_sched_barrier(0);
    __builtin_amdgcn_s_barrier();
  }

  const int ci = (l >> 4) * 4;
  const int cj = l & 15;

  if constexpr (EPI == 1) {
    // ---- U = exp(acc*scale) + deterministic partial row-sums ----
    bf16* sp = (bf16*)Cp;
    float* part = (float*)As;          // reuse LDS: part[wc*256 + localrow]
    #pragma unroll
    for (int mf = 0; mf < 8; ++mf) {
      const int lr0 = wr * 128 + mf * 16 + ci;   // tile-local row
      #pragma unroll
      for (int r = 0; r < 4; ++r) {
        float s = 0.f;
        #pragma unroll
        for (int nf = 0; nf < 4; ++nf) {
          const int j = col0 + wc * 64 + nf * 16 + cj;
          const float u = __expf(acc[mf][nf][r] * scale);
          const bf16 ub = (bf16)u;
          sp[(row0 + lr0 + r) * NPIX + j] = ub;
          s += (float)ub;
        }
        s += __shfl_xor(s, 1); s += __shfl_xor(s, 2);
        s += __shfl_xor(s, 4); s += __shfl_xor(s, 8);
        if (cj == 0) part[wc * 256 + lr0 + r] = s;
      }
    }
    __syncthreads();
    if (t < 256)
      pst[((long long)z * 4 + by) * 1024 + row0 + t]
          = part[t] + part[256 + t] + part[512 + t] + part[768 + t];
    return;
  }

  #pragma unroll
  for (int mf = 0; mf < 8; ++mf) {
    const int i0 = row0 + wr * 128 + mf * 16 + ci;
    if constexpr (EPI == 2) {
      const float* pz = pst + (long long)z * 4096;
      #pragma unroll
      for (int r = 0; r < 4; ++r) {
        const int row = i0 + r;
        const float is = 1.f / (pz[row] + pz[1024 + row] +
                                pz[2048 + row] + pz[3072 + row]);
        bf16* hp = (bf16*)Cp;
        #pragma unroll
        for (int nf = 0; nf < 4; ++nf) {
          const int j = col0 + wc * 64 + nf * 16 + cj;
          hp[row * CCH + j] = (bf16)(acc[mf][nf][r] * is);
        }
      }
    } else {
      #pragma unroll
      for (int nf = 0; nf < 4; ++nf) {
        const int j = col0 + wc * 64 + nf * 16 + cj;
        const f32x4 a = acc[mf][nf];
        if constexpr (EPI == 0) {
          const float bj = bias[j];
          if (j < NPIX) {
            bf16* q = (bf16*)Cp;
            #pragma unroll
            for (int r = 0; r < 4; ++r)
              q[(i0 + r) * NPIX + j] = (bf16)(a[r] + bj);
          } else {
            bf16* vb = (bf16*)C2p;
            #pragma unroll
            for (int r = 0; r < 4; ++r)
              vb[(j - NPIX) * NPIX + (i0 + r)] = (bf16)(a[r] + bj);
          }
        } else {
          float* op = (float*)Cp;
          #pragma unroll
          for (int r = 0; r < 4; ++r)
            op[(i0 + r) * NPIX + j] = a[r] + bias[i0 + r] + residb[(i0 + r) * NPIX + j];
        }
      }
    }
  }
}

// ---- fused GroupNorm: one block per (batch,group); 16ch x 1024px in LDS,
//      stats + normalize + transpose-write hnT[n][c] (bf16) in one pass ----
__global__ __launch_bounds__(256)
void gn_fused(const float* __restrict__ x, const float* __restrict__ gw,
              const float* __restrict__ gb, bf16* __restrict__ hnT)
{
  __shared__ float xs[16 * 1024];   // 64 KB
  __shared__ float red[8];
  const int b = blockIdx.x >> 5;
  const int g = blockIdx.x & 31;
  const float* xp = x + ((long long)b * CCH + g * 16) * NPIX;
  const int t = threadIdx.x;

  float4* xsv = (float4*)xs;
  const float4* gv = (const float4*)xp;
  float s = 0.f, ss = 0.f;
  #pragma unroll
  for (int i = 0; i < 16; ++i) {
    float4 v = gv[t + i * 256];
    xsv[t + i * 256] = v;
    s  += v.x + v.y + v.z + v.w;
    ss += v.x * v.x + v.y * v.y + v.z * v.z + v.w * v.w;
  }
  #pragma unroll
  for (int o = 32; o; o >>= 1) { s += __shfl_xor(s, o); ss += __shfl_xor(ss, o); }
  if ((t & 63) == 0) { red[t >> 6] = s; red[4 + (t >> 6)] = ss; }
  __syncthreads();
  s  = red[0] + red[1] + red[2] + red[3];
  ss = red[4] + red[5] + red[6] + red[7];
  const float mean = s * (1.f / 16384.f);
  const float var  = ss * (1.f / 16384.f) - mean * mean;
  const float rstd = rsqrtf(var + 1e-5f);

  float ac[16], bc[16];
  #pragma unroll
  for (int c = 0; c < 16; ++c) {
    const float wv = gw[g * 16 + c] * rstd;
    ac[c] = wv;
    bc[c] = gb[g * 16 + c] - mean * wv;
  }

  bf16* hp = hnT + (long long)b * 1048576;   // 2MB slab stride (aliased region)
  hp += g * 16;
  #pragma unroll
  for (int r = 0; r < 4; ++r) {
    const int n = t + r * 256;
    bf16x8 o0, o1;
    #pragma unroll
    for (int c = 0; c < 8; ++c)
      o0[c] = (bf16)(xs[c * 1024 + n] * ac[c] + bc[c]);
    #pragma unroll
    for (int c = 0; c < 8; ++c)
      o1[c] = (bf16)(xs[(8 + c) * 1024 + n] * ac[8 + c] + bc[8 + c]);
    *(bf16x8*)&hp[(long long)n * CCH]     = o0;
    *(bf16x8*)&hp[(long long)n * CCH + 8] = o1;
  }
}

// ---- fp32 -> bf16 weight conversion (once) ----
__global__ __launch_bounds__(256)
void cvt_weights(const float* __restrict__ qw, const float* __restrict__ pw,
                 bf16* __restrict__ qwb, bf16* __restrict__ pwb)
{
  const int i = blockIdx.x * 256 + threadIdx.x;
  if (i < 3 * CCH * CCH) qwb[i] = (bf16)qw[i];
  if (i < CCH * CCH) pwb[i] = (bf16)pw[i];
}

extern "C" void kernel_launch(void* const* d_in, const int* in_sizes, int n_in,
                              void* d_out, int out_size, void* d_ws, size_t ws_size,
                              hipStream_t stream)
{
  const float* x      = (const float*)d_in[0];
  const float* gn_w   = (const float*)d_in[1];
  const float* gn_b   = (const float*)d_in[2];
  const float* qkv_w  = (const float*)d_in[3];
  const float* qkv_b  = (const float*)d_in[4];
  const float* proj_w = (const float*)d_in[5];
  const float* proj_b = (const float*)d_in[6];
  float* out = (float*)d_out;
  (void)in_sizes; (void)n_in; (void)out_size;

  char* ws = (char*)d_ws;
  size_t off = 0;
  auto alloc = [&](size_t bytes) -> char* {
    char* p = ws + off;
    off += (bytes + 255) & ~(size_t)255;
    return p;
  };
  bf16* qkv_wb  = (bf16*)alloc(3 * 512 * 512 * 2);
  bf16* proj_wb = (bf16*)alloc(512 * 512 * 2);
  const size_t fixed = off;
  // per-batch (with aliasing): hnT/ubuf union 2MB + qkT/hvT union 2MB
  //                            + vbuf 1MB + pst 16KB
  const size_t per = 2097152ull + 2097152ull + 1048576ull + 16384ull;
  int Bc = 32;
  if (ws_size > fixed) {
    size_t fit = (ws_size - fixed) / per;
    if (fit < 32) Bc = (int)fit;
  } else {
    Bc = 0;
  }
  if (Bc < 1) Bc = 1;

  // aliased regions (safe by in-stream ordering):
  //   hnT (1MB, dead after QKV)  aliases  ubuf (2MB, written by U)
  //   qkT (2MB, dead after U)    aliases  hvT (1MB, written by PV)
  // Slab stride: 2MB = 1048576 bf16 elements for both regions.
  char* regA = alloc((size_t)Bc * 2097152);   // hnT / ubuf
  char* regB = alloc((size_t)Bc * 2097152);   // qkT / hvT
  bf16*  vbuf   = (bf16*) alloc((size_t)Bc * 1048576);
  float* pstats = (float*)alloc((size_t)Bc * 16384);
  bf16* hnT  = (bf16*)regA;
  bf16* ubuf = (bf16*)regA;
  bf16* qkT  = (bf16*)regB;
  bf16* hvT  = (bf16*)regB;

  cvt_weights<<<dim3(3072), 256, 0, stream>>>(qkv_w, proj_w, qkv_wb, proj_wb);

  const float scale = 0.044194173824159216f;  // 512^-0.5
  for (int b0 = 0; b0 < 32; b0 += Bc) {
    const int bc = (32 - b0 < Bc) ? (32 - b0) : Bc;
    const float* xb = x + (size_t)b0 * CN;

    gn_fused<<<dim3(bc * 32), 256, 0, stream>>>(xb, gn_w, gn_b, hnT);

    // QKV: [n][o] = hnT[n][c] . qkv_w[o][c];  q,k -> qkT, v -> vbuf[c][m]
    // hnT element stride 1048576 (2MB slab)
    gemm_bt<0><<<dim3(4, 6, bc), 512, 0, stream>>>(
        hnT, 512, 1048576, qkv_wb, 512, 0,
        (char*)qkT, 2097152, (char*)vbuf, 1048576, qkv_b, nullptr, nullptr,
        512, 1.f);

    // U[n][m] = exp(q[n].k[m] * scale)  (bf16) + partial row sums -> pstats
    gemm_bt<1><<<dim3(4, 4, bc), 512, 0, stream>>>(
        qkT, 1024, 1048576, qkT + 512, 1024, 1048576,
        (char*)ubuf, 2097152, nullptr, 0, nullptr, nullptr, pstats,
        512, scale);

    // hvT[n][c] = (U[n][:] . v[c][:]) / rowsum[n]
    // ubuf element stride 1048576 (2MB slab)  [r13 bug: was 2097152]
    gemm_bt<2><<<dim3(4, 2, bc), 512, 0, stream>>>(
        ubuf, 1024, 1048576, vbuf, 1024, 524288,
        (char*)hvT, 2097152, nullptr, 0, nullptr, nullptr, pstats,
        1024, 1.f);

    // out[c][n] = proj_w[c][:] . hvT[n][:] + proj_b[c] + x[c][n]
    // hvT element stride 1048576 (2MB slab)
    gemm_bt<3><<<dim3(2, 4, bc), 512, 0, stream>>>(
        proj_wb, 512, 0, hvT, 512, 1048576,
        (char*)(out + (size_t)b0 * CN), 2097152, nullptr, 0, proj_b, xb,
        nullptr, 512, 1.f);
  }
}